// Round 2
// baseline (626.124 us; speedup 1.0000x reference)
//
#include <hip/hip_runtime.h>

#define NPTS 65536          // B*N = 32*2048
#define HH 256
#define DIN 131
#define LAT 128
#define STEPS 5
#define DT 0.2f
#define P 32                // points per block
#define PADK 264            // padded row length (bf16 elems)

typedef unsigned int uint;
typedef unsigned short ushort;
typedef __attribute__((ext_vector_type(8))) short short8;
typedef __attribute__((ext_vector_type(4))) float floatx4;

__device__ __forceinline__ float tanh_fast(float x) {
    // tanh(x) = 1 - 2/(exp2(2x*log2e)+1); exact at both saturated ends.
    float e = __builtin_amdgcn_exp2f(x * 2.8853900817779268f);
    return 1.0f - 2.0f * __builtin_amdgcn_rcpf(e + 1.0f);
}

__device__ __forceinline__ ushort f2bf(float f) {
    uint u = __builtin_bit_cast(uint, f);
    u += 0x7fffu + ((u >> 16) & 1u);   // RNE
    return (ushort)(u >> 16);
}

// pack two f32 -> bf16x2 (RNE) with a single v_perm_b32 merge
__device__ __forceinline__ uint packbf2(float a, float b) {
    uint ua = __builtin_bit_cast(uint, a); ua += 0x7fffu + ((ua >> 16) & 1u);
    uint ub = __builtin_bit_cast(uint, b); ub += 0x7fffu + ((ub >> 16) & 1u);
    // D = [ub.hi16 : ua.hi16]  (sel bytes: S1.b2,S1.b3,S0.b2,S0.b3)
    return __builtin_amdgcn_perm(ub, ua, 0x07060302u);
}

// prep:
//  a1[b][h] = b1[h] + sum_l z[b][l]*W1[h][3+l];  rs[h] = sum_l W1[h][3+l]
//  wsw0 = W2  as bf16 B-frags: frag[((nt*8+kt)*64+lane)*8+i] = M[nt*16+(lane&15)][kt*32+(lane>>4)*8+i]
//  wswd = W2d where W2d[j][h] = W2[j][h]*(W1[h][0]*W3[0][j] + W1[h][1]*W3[1][j])
//  (folds both tangent GEMMs into one: div = g2 @ (g1 @ W2d^T) elementwise-summed)
__global__ void prep_kernel(const float* __restrict__ z, const float* __restrict__ W1,
                            const float* __restrict__ b1, const float* __restrict__ W2,
                            const float* __restrict__ W3,
                            float* __restrict__ a1, float* __restrict__ rsv,
                            ushort* __restrict__ wsw0, ushort* __restrict__ wswd)
{
    int tid = blockIdx.x * 256 + threadIdx.x;
    if (tid < 8192) {
        int b = tid >> 8, h = tid & 255;
        const float* wrow = W1 + h * DIN + 3;
        const float* zb = z + b * LAT;
        float s = b1[h], r = 0.f;
        for (int l = 0; l < LAT; ++l) { float wv = wrow[l]; s += wv * zb[l]; r += wv; }
        a1[tid] = s;
        if (b == 0) rsv[h] = r;
    } else {
        int t = tid - 8192;                    // 0..8191
        int lane = t & 63, kt = (t >> 6) & 7, nt = t >> 9;
        int j = nt * 16 + (lane & 15);
        int k0 = kt * 32 + (lane >> 4) * 8;
        float w30 = W3[j], w31 = W3[HH + j];
        const float* src = W2 + j * HH + k0;
        ushort* d0 = wsw0 + t * 8;
        ushort* dd = wswd + t * 8;
        #pragma unroll
        for (int i = 0; i < 8; ++i) {
            int k = k0 + i;
            float wv = src[i];
            d0[i] = f2bf(wv);
            dd[i] = f2bf(wv * (W1[k * DIN] * w30 + W1[k * DIN + 1] * w31));
        }
    }
}

__global__ __launch_bounds__(256, 4) void cnf_kernel(
        const float* __restrict__ xin, const float* __restrict__ W1,
        const float* __restrict__ b2, const float* __restrict__ W3,
        const float* __restrict__ b3, const float* __restrict__ osc,
        const float* __restrict__ a1, const float* __restrict__ rsv,
        const ushort* __restrict__ wsw0, const ushort* __restrict__ wswd,
        float* __restrict__ out)
{
    __shared__ __align__(16) ushort V[2][P][PADK];   // V0=h1, V1=g1 (bf16)
    __shared__ float a1s[HH], rsS[HH], wx0s[HH], wx1s[HH], wts[HH];
    __shared__ float X0[P], X1[P], C[P];
    __shared__ float sums[4][P][3];                  // per-wave partial [v0,v1,div]

    const int tid = threadIdx.x;
    const int lane = tid & 63;
    const int w = tid >> 6;
    const int r15 = lane & 15;
    const int q = lane >> 4;
    const int blk = blockIdx.x;
    const int b = blk >> 6;                          // 64 blocks per batch
    const int pbase = blk * P;

    if (tid < HH) {
        a1s[tid] = a1[b * HH + tid];
        rsS[tid] = rsv[tid];
        wx0s[tid] = W1[tid * DIN + 0];
        wx1s[tid] = W1[tid * DIN + 1];
        wts[tid]  = W1[tid * DIN + 2];
    }
    if (tid < P) {
        int gp = pbase + tid;
        X0[tid] = xin[gp * 2 + 0];
        X1[tid] = xin[gp * 2 + 1];
        C[tid] = 0.f;                                // log_det == ctx-accumulator
    }
    const float os = osc[0];
    const float b30 = b3[0], b31 = b3[1];
    float w30r[4], w31r[4], b2r[4];
    #pragma unroll
    for (int n = 0; n < 4; ++n) {
        int j = (w * 4 + n) * 16 + r15;              // this lane's output column
        w30r[n] = W3[j];
        w31r[n] = W3[HH + j];
        b2r[n] = b2[j];
    }
    const ushort* bp0 = wsw0 + (size_t)(w * 4) * 4096 + (size_t)lane * 8;
    const ushort* bpd = wswd + (size_t)(w * 4) * 4096 + (size_t)lane * 8;
    __syncthreads();

    const int hp = tid & 127;
    const int h0 = hp * 2;
    const int pst = tid >> 7;

    for (int s = 0; s < STEPS; ++s) {
        const float tcur = (float)s * DT;

        // ---- phase 1: collapsed layer-1; store h1 and g1 as bf16 A-tiles ----
        {
            float wa = wx0s[h0], wb = wx0s[h0 + 1];
            float wc = wx1s[h0], wd = wx1s[h0 + 1];
            float ra = rsS[h0],  rb = rsS[h0 + 1];
            float ba  = a1s[h0]     + wts[h0]     * tcur;
            float bbv = a1s[h0 + 1] + wts[h0 + 1] * tcur;
            #pragma unroll
            for (int i = 0; i < 16; ++i) {
                int p = pst + 2 * i;
                float x0 = X0[p], x1 = X1[p], cc = C[p];
                float pa = ba  + wa * x0 + wc * x1 + ra * cc;
                float pb = bbv + wb * x0 + wd * x1 + rb * cc;
                float ha = tanh_fast(pa), hb = tanh_fast(pb);
                float ga = 1.f - ha * ha, gb = 1.f - hb * hb;
                *(uint*)&V[0][p][h0] = packbf2(ha, hb);
                *(uint*)&V[1][p][h0] = packbf2(ga, gb);
            }
        }
        __syncthreads();

        // ---- GEMMs: R0 = h1 @ W2^T, Rd = g1 @ W2d^T  (mfma 16x16x32 bf16) ----
        floatx4 acc[2][2][4];                        // [mat][mt][n]
        #pragma unroll
        for (int m = 0; m < 2; ++m)
            #pragma unroll
            for (int mt = 0; mt < 2; ++mt)
                #pragma unroll
                for (int n = 0; n < 4; ++n)
                    acc[m][mt][n] = (floatx4){0.f, 0.f, 0.f, 0.f};

        #pragma unroll
        for (int kt = 0; kt < 8; ++kt) {
            const int koff = kt * 32 + q * 8;
            #pragma unroll
            for (int m = 0; m < 2; ++m) {
                short8 af0 = *(const short8*)&V[m][r15][koff];
                short8 af1 = *(const short8*)&V[m][16 + r15][koff];
                const ushort* bp = (m == 0 ? bp0 : bpd) + (size_t)kt * 512;
                #pragma unroll
                for (int n = 0; n < 4; ++n) {
                    short8 bfr = *(const short8*)(bp + (size_t)n * 4096);
                    acc[m][0][n] = __builtin_amdgcn_mfma_f32_16x16x32_bf16(af0, bfr, acc[m][0][n], 0, 0, 0);
                    acc[m][1][n] = __builtin_amdgcn_mfma_f32_16x16x32_bf16(af1, bfr, acc[m][1][n], 0, 0, 0);
                }
            }
        }

        // ---- epilogue: h2/g2, project with W3 (v) + folded div, reduce j ----
        #pragma unroll
        for (int mt = 0; mt < 2; ++mt) {
            float sv0[4] = {0,0,0,0}, sv1[4] = {0,0,0,0}, sdv[4] = {0,0,0,0};
            #pragma unroll
            for (int n = 0; n < 4; ++n) {
                float w0 = w30r[n], w1 = w31r[n], bbj = b2r[n];
                #pragma unroll
                for (int r = 0; r < 4; ++r) {
                    float h2 = tanh_fast(acc[0][mt][n][r] + bbj);
                    float g2 = 1.f - h2 * h2;
                    sv0[r] += h2 * w0;
                    sv1[r] += h2 * w1;
                    sdv[r] += g2 * acc[1][mt][n][r];
                }
            }
            #pragma unroll
            for (int r = 0; r < 4; ++r) {
                float ta = sv0[r], tb = sv1[r], td = sdv[r];
                #pragma unroll
                for (int off = 1; off < 16; off <<= 1) {
                    ta += __shfl_xor(ta, off);
                    tb += __shfl_xor(tb, off);
                    td += __shfl_xor(td, off);
                }
                if (r15 == 0) {
                    int p = mt * 16 + q * 4 + r;
                    sums[w][p][0] = ta;
                    sums[w][p][1] = tb;
                    sums[w][p][2] = td;
                }
            }
        }
        __syncthreads();

        // ---- state update (Euler) ----
        if (tid < P) {
            float s0 = sums[0][tid][0] + sums[1][tid][0] + sums[2][tid][0] + sums[3][tid][0];
            float s1 = sums[0][tid][1] + sums[1][tid][1] + sums[2][tid][1] + sums[3][tid][1];
            float sd = sums[0][tid][2] + sums[1][tid][2] + sums[2][tid][2] + sums[3][tid][2];
            X0[tid] += (s0 + b30) * os * DT;
            X1[tid] += (s1 + b31) * os * DT;
            C[tid]  += sd * os * DT;
        }
        __syncthreads();
    }

    if (tid < P) {
        int gp = pbase + tid;
        out[gp * 2 + 0] = X0[tid];
        out[gp * 2 + 1] = X1[tid];
        out[NPTS * 2 + gp] = C[tid];      // log_det == C
    }
}

extern "C" void kernel_launch(void* const* d_in, const int* in_sizes, int n_in,
                              void* d_out, int out_size, void* d_ws, size_t ws_size,
                              hipStream_t stream) {
    const float* x   = (const float*)d_in[0];
    const float* z   = (const float*)d_in[1];
    const float* W1  = (const float*)d_in[2];
    const float* b1  = (const float*)d_in[3];
    const float* W2  = (const float*)d_in[4];
    const float* b2  = (const float*)d_in[5];
    const float* W3  = (const float*)d_in[6];
    const float* b3  = (const float*)d_in[7];
    const float* osc = (const float*)d_in[8];

    // ws: a1 [8192 f]@0 | rsv [256 f]@32768B | wsw0 [65536 bf16]@33792B | wswd @164864B
    float* a1   = (float*)d_ws;
    float* rsv  = a1 + 8192;
    ushort* wsw0 = (ushort*)((char*)d_ws + 33792);
    ushort* wswd = (ushort*)((char*)d_ws + 164864);

    hipLaunchKernelGGL(prep_kernel, dim3(64), dim3(256), 0, stream,
                       z, W1, b1, W2, W3, a1, rsv, wsw0, wswd);
    hipLaunchKernelGGL(cnf_kernel, dim3(2048), dim3(256), 0, stream,
                       x, W1, b2, W3, b3, osc, a1, rsv, wsw0, wswd, (float*)d_out);
}

// Round 3
// 579.061 us; speedup vs baseline: 1.0813x; 1.0813x over previous
//
#include <hip/hip_runtime.h>

#define NPTS 65536          // B*N = 32*2048
#define HH 256
#define DIN 131
#define LAT 128
#define STEPS 5
#define DT 0.2f
#define P 32                // points per block
#define PADK 264            // padded row length (bf16 elems)

typedef unsigned int uint;
typedef unsigned short ushort;
typedef __attribute__((ext_vector_type(8))) short short8;
typedef __attribute__((ext_vector_type(4))) float floatx4;

__device__ __forceinline__ float tanh_fast(float x) {
    // tanh(x) = 1 - 2/(exp2(2x*log2e)+1); exact at both saturated ends.
    float e = __builtin_amdgcn_exp2f(x * 2.8853900817779268f);
    return 1.0f - 2.0f * __builtin_amdgcn_rcpf(e + 1.0f);
}

__device__ __forceinline__ ushort f2bf(float f) {
    uint u = __builtin_bit_cast(uint, f);
    u += 0x7fffu + ((u >> 16) & 1u);   // RNE
    return (ushort)(u >> 16);
}

// pack two f32 -> bf16x2 (RNE) with a single v_perm_b32 merge
__device__ __forceinline__ uint packbf2(float a, float b) {
    uint ua = __builtin_bit_cast(uint, a); ua += 0x7fffu + ((ua >> 16) & 1u);
    uint ub = __builtin_bit_cast(uint, b); ub += 0x7fffu + ((ub >> 16) & 1u);
    return __builtin_amdgcn_perm(ub, ua, 0x07060302u);
}

// prep:
//  a1[b][h] = b1[h] + sum_l z[b][l]*W1[h][3+l];  rs[h] = sum_l W1[h][3+l]
//  wsw0 = W2  as bf16 B-frags: frag[((nt*8+kt)*64+lane)*8+i] = M[nt*16+(lane&15)][kt*32+(lane>>4)*8+i]
//  wswd = W2d where W2d[j][h] = W2[j][h]*(W1[h][0]*W3[0][j] + W1[h][1]*W3[1][j])
//  (folds both tangent GEMMs into one: div = sum_j g2[j] * (g1 @ W2d^T)[j])
__global__ void prep_kernel(const float* __restrict__ z, const float* __restrict__ W1,
                            const float* __restrict__ b1, const float* __restrict__ W2,
                            const float* __restrict__ W3,
                            float* __restrict__ a1, float* __restrict__ rsv,
                            ushort* __restrict__ wsw0, ushort* __restrict__ wswd)
{
    int tid = blockIdx.x * 256 + threadIdx.x;
    if (tid < 8192) {
        int b = tid >> 8, h = tid & 255;
        const float* wrow = W1 + h * DIN + 3;
        const float* zb = z + b * LAT;
        float s = b1[h], r = 0.f;
        for (int l = 0; l < LAT; ++l) { float wv = wrow[l]; s += wv * zb[l]; r += wv; }
        a1[tid] = s;
        if (b == 0) rsv[h] = r;
    } else {
        int t = tid - 8192;                    // 0..8191
        int lane = t & 63, kt = (t >> 6) & 7, nt = t >> 9;
        int j = nt * 16 + (lane & 15);
        int k0 = kt * 32 + (lane >> 4) * 8;
        float w30 = W3[j], w31 = W3[HH + j];
        const float* src = W2 + j * HH + k0;
        ushort* d0 = wsw0 + t * 8;
        ushort* dd = wswd + t * 8;
        #pragma unroll
        for (int i = 0; i < 8; ++i) {
            int k = k0 + i;
            float wv = src[i];
            d0[i] = f2bf(wv);
            dd[i] = f2bf(wv * (W1[k * DIN] * w30 + W1[k * DIN + 1] * w31));
        }
    }
}

// __launch_bounds__(256,3): budget ~168 VGPRs/wave. Natural demand is
// 64 acc (unified AGPR) + ~75 arch = ~140 — fits WITHOUT spilling.
// (256,4) = 128-reg budget spilled to scratch -> 1.3 GB HBM fetch, 2.5x slower (R2).
__global__ __launch_bounds__(256, 3) void cnf_kernel(
        const float* __restrict__ xin, const float* __restrict__ W1,
        const float* __restrict__ b2, const float* __restrict__ W3,
        const float* __restrict__ b3, const float* __restrict__ osc,
        const float* __restrict__ a1, const float* __restrict__ rsv,
        const ushort* __restrict__ wsw0, const ushort* __restrict__ wswd,
        float* __restrict__ out)
{
    __shared__ __align__(16) ushort V[2][P][PADK];   // V0=h1, V1=g1 (bf16)
    __shared__ float a1s[HH], rsS[HH], wx0s[HH], wx1s[HH], wts[HH];
    __shared__ float X0[P], X1[P], C[P];
    __shared__ float sums[4][P][3];                  // per-wave partial [v0,v1,div]

    const int tid = threadIdx.x;
    const int lane = tid & 63;
    const int w = tid >> 6;
    const int r15 = lane & 15;
    const int q = lane >> 4;
    const int blk = blockIdx.x;
    const int b = blk >> 6;                          // 64 blocks per batch
    const int pbase = blk * P;

    if (tid < HH) {
        a1s[tid] = a1[b * HH + tid];
        rsS[tid] = rsv[tid];
        wx0s[tid] = W1[tid * DIN + 0];
        wx1s[tid] = W1[tid * DIN + 1];
        wts[tid]  = W1[tid * DIN + 2];
    }
    if (tid < P) {
        int gp = pbase + tid;
        X0[tid] = xin[gp * 2 + 0];
        X1[tid] = xin[gp * 2 + 1];
        C[tid] = 0.f;                                // log_det == ctx-accumulator
    }
    const float os = osc[0];
    const float b30 = b3[0], b31 = b3[1];
    float w30r[4], w31r[4], b2r[4];
    #pragma unroll
    for (int n = 0; n < 4; ++n) {
        int j = (w * 4 + n) * 16 + r15;              // this lane's output column
        w30r[n] = W3[j];
        w31r[n] = W3[HH + j];
        b2r[n] = b2[j];
    }
    const ushort* bp0 = wsw0 + (size_t)(w * 4) * 4096 + (size_t)lane * 8;
    const ushort* bpd = wswd + (size_t)(w * 4) * 4096 + (size_t)lane * 8;
    __syncthreads();

    const int hp = tid & 127;
    const int h0 = hp * 2;
    const int pst = tid >> 7;

    for (int s = 0; s < STEPS; ++s) {
        const float tcur = (float)s * DT;

        // ---- phase 1: collapsed layer-1; store h1 and g1 as bf16 A-tiles ----
        {
            float wa = wx0s[h0], wb = wx0s[h0 + 1];
            float wc = wx1s[h0], wd = wx1s[h0 + 1];
            float ra = rsS[h0],  rb = rsS[h0 + 1];
            float ba  = a1s[h0]     + wts[h0]     * tcur;
            float bbv = a1s[h0 + 1] + wts[h0 + 1] * tcur;
            #pragma unroll
            for (int i = 0; i < 16; ++i) {
                int p = pst + 2 * i;
                float x0 = X0[p], x1 = X1[p], cc = C[p];
                float pa = ba  + wa * x0 + wc * x1 + ra * cc;
                float pb = bbv + wb * x0 + wd * x1 + rb * cc;
                float ha = tanh_fast(pa), hb = tanh_fast(pb);
                float ga = 1.f - ha * ha, gb = 1.f - hb * hb;
                *(uint*)&V[0][p][h0] = packbf2(ha, hb);
                *(uint*)&V[1][p][h0] = packbf2(ga, gb);
            }
        }
        __syncthreads();

        // ---- GEMMs: R0 = h1 @ W2^T, Rd = g1 @ W2d^T  (mfma 16x16x32 bf16) ----
        floatx4 acc[2][2][4];                        // [mat][mt][n]
        #pragma unroll
        for (int m = 0; m < 2; ++m)
            #pragma unroll
            for (int mt = 0; mt < 2; ++mt)
                #pragma unroll
                for (int n = 0; n < 4; ++n)
                    acc[m][mt][n] = (floatx4){0.f, 0.f, 0.f, 0.f};

        #pragma unroll
        for (int kt = 0; kt < 8; ++kt) {
            const int koff = kt * 32 + q * 8;
            #pragma unroll
            for (int m = 0; m < 2; ++m) {
                short8 af0 = *(const short8*)&V[m][r15][koff];
                short8 af1 = *(const short8*)&V[m][16 + r15][koff];
                const ushort* bp = (m == 0 ? bp0 : bpd) + (size_t)kt * 512;
                #pragma unroll
                for (int n = 0; n < 4; ++n) {
                    short8 bfr = *(const short8*)(bp + (size_t)n * 4096);
                    acc[m][0][n] = __builtin_amdgcn_mfma_f32_16x16x32_bf16(af0, bfr, acc[m][0][n], 0, 0, 0);
                    acc[m][1][n] = __builtin_amdgcn_mfma_f32_16x16x32_bf16(af1, bfr, acc[m][1][n], 0, 0, 0);
                }
            }
        }

        // ---- epilogue: h2/g2, project with W3 (v) + folded div, reduce j ----
        #pragma unroll
        for (int mt = 0; mt < 2; ++mt) {
            float sv0[4] = {0,0,0,0}, sv1[4] = {0,0,0,0}, sdv[4] = {0,0,0,0};
            #pragma unroll
            for (int n = 0; n < 4; ++n) {
                float w0 = w30r[n], w1 = w31r[n], bbj = b2r[n];
                #pragma unroll
                for (int r = 0; r < 4; ++r) {
                    float h2 = tanh_fast(acc[0][mt][n][r] + bbj);
                    float g2 = 1.f - h2 * h2;
                    sv0[r] += h2 * w0;
                    sv1[r] += h2 * w1;
                    sdv[r] += g2 * acc[1][mt][n][r];
                }
            }
            #pragma unroll
            for (int r = 0; r < 4; ++r) {
                float ta = sv0[r], tb = sv1[r], td = sdv[r];
                #pragma unroll
                for (int off = 1; off < 16; off <<= 1) {
                    ta += __shfl_xor(ta, off);
                    tb += __shfl_xor(tb, off);
                    td += __shfl_xor(td, off);
                }
                if (r15 == 0) {
                    int p = mt * 16 + q * 4 + r;
                    sums[w][p][0] = ta;
                    sums[w][p][1] = tb;
                    sums[w][p][2] = td;
                }
            }
        }
        __syncthreads();

        // ---- state update (Euler) ----
        if (tid < P) {
            float s0 = sums[0][tid][0] + sums[1][tid][0] + sums[2][tid][0] + sums[3][tid][0];
            float s1 = sums[0][tid][1] + sums[1][tid][1] + sums[2][tid][1] + sums[3][tid][1];
            float sd = sums[0][tid][2] + sums[1][tid][2] + sums[2][tid][2] + sums[3][tid][2];
            X0[tid] += (s0 + b30) * os * DT;
            X1[tid] += (s1 + b31) * os * DT;
            C[tid]  += sd * os * DT;
        }
        __syncthreads();
    }

    if (tid < P) {
        int gp = pbase + tid;
        out[gp * 2 + 0] = X0[tid];
        out[gp * 2 + 1] = X1[tid];
        out[NPTS * 2 + gp] = C[tid];      // log_det == C
    }
}

extern "C" void kernel_launch(void* const* d_in, const int* in_sizes, int n_in,
                              void* d_out, int out_size, void* d_ws, size_t ws_size,
                              hipStream_t stream) {
    const float* x   = (const float*)d_in[0];
    const float* z   = (const float*)d_in[1];
    const float* W1  = (const float*)d_in[2];
    const float* b1  = (const float*)d_in[3];
    const float* W2  = (const float*)d_in[4];
    const float* b2  = (const float*)d_in[5];
    const float* W3  = (const float*)d_in[6];
    const float* b3  = (const float*)d_in[7];
    const float* osc = (const float*)d_in[8];

    // ws: a1 [8192 f]@0 | rsv [256 f]@32768B | wsw0 [65536 bf16]@33792B | wswd @164864B
    float* a1   = (float*)d_ws;
    float* rsv  = a1 + 8192;
    ushort* wsw0 = (ushort*)((char*)d_ws + 33792);
    ushort* wswd = (ushort*)((char*)d_ws + 164864);

    hipLaunchKernelGGL(prep_kernel, dim3(64), dim3(256), 0, stream,
                       z, W1, b1, W2, W3, a1, rsv, wsw0, wswd);
    hipLaunchKernelGGL(cnf_kernel, dim3(2048), dim3(256), 0, stream,
                       x, W1, b2, W3, b3, osc, a1, rsv, wsw0, wswd, (float*)d_out);
}

// Round 4
// 402.747 us; speedup vs baseline: 1.5546x; 1.4378x over previous
//
#include <hip/hip_runtime.h>

#define NPTS 65536          // B*N = 32*2048
#define HH 256
#define DIN 131
#define LAT 128
#define STEPS 5
#define DT 0.2f
#define P 32                // points per block
#define PADK 264            // padded row length (bf16 elems)

typedef unsigned int uint;
typedef unsigned short ushort;
typedef __attribute__((ext_vector_type(8))) short short8;
typedef __attribute__((ext_vector_type(4))) float floatx4;

__device__ __forceinline__ float tanh_fast(float x) {
    // tanh(x) = 1 - 2/(exp2(2x*log2e)+1); exact at both saturated ends.
    float e = __builtin_amdgcn_exp2f(x * 2.8853900817779268f);
    return 1.0f - 2.0f * __builtin_amdgcn_rcpf(e + 1.0f);
}

__device__ __forceinline__ ushort f2bf(float f) {
    uint u = __builtin_bit_cast(uint, f);
    u += 0x7fffu + ((u >> 16) & 1u);   // RNE
    return (ushort)(u >> 16);
}

// pack two f32 -> bf16x2 (RNE) with a single v_perm_b32 merge
__device__ __forceinline__ uint packbf2(float a, float b) {
    uint ua = __builtin_bit_cast(uint, a); ua += 0x7fffu + ((ua >> 16) & 1u);
    uint ub = __builtin_bit_cast(uint, b); ub += 0x7fffu + ((ub >> 16) & 1u);
    return __builtin_amdgcn_perm(ub, ua, 0x07060302u);
}

// prep:
//  a1[b][h] = b1[h] + sum_l z[b][l]*W1[h][3+l];  rs[h] = sum_l W1[h][3+l]
//  wsw0 = W2  as bf16 B-frags: frag[((nt*8+kt)*64+lane)*8+i] = M[nt*16+(lane&15)][kt*32+(lane>>4)*8+i]
//  wswd = W2d where W2d[j][h] = W2[j][h]*(W1[h][0]*W3[0][j] + W1[h][1]*W3[1][j])
//  (folds both tangent GEMMs into one: div = sum_j g2[j] * (g1 @ W2d^T)[j])
__global__ void prep_kernel(const float* __restrict__ z, const float* __restrict__ W1,
                            const float* __restrict__ b1, const float* __restrict__ W2,
                            const float* __restrict__ W3,
                            float* __restrict__ a1, float* __restrict__ rsv,
                            ushort* __restrict__ wsw0, ushort* __restrict__ wswd)
{
    int tid = blockIdx.x * 256 + threadIdx.x;
    if (tid < 8192) {
        int b = tid >> 8, h = tid & 255;
        const float* wrow = W1 + h * DIN + 3;
        const float* zb = z + b * LAT;
        float s = b1[h], r = 0.f;
        for (int l = 0; l < LAT; ++l) { float wv = wrow[l]; s += wv * zb[l]; r += wv; }
        a1[tid] = s;
        if (b == 0) rsv[h] = r;
    } else {
        int t = tid - 8192;                    // 0..8191
        int lane = t & 63, kt = (t >> 6) & 7, nt = t >> 9;
        int j = nt * 16 + (lane & 15);
        int k0 = kt * 32 + (lane >> 4) * 8;
        float w30 = W3[j], w31 = W3[HH + j];
        const float* src = W2 + j * HH + k0;
        ushort* d0 = wsw0 + t * 8;
        ushort* dd = wswd + t * 8;
        #pragma unroll
        for (int i = 0; i < 8; ++i) {
            int k = k0 + i;
            float wv = src[i];
            d0[i] = f2bf(wv);
            dd[i] = f2bf(wv * (W1[k * DIN] * w30 + W1[k * DIN + 1] * w31));
        }
    }
}

// __launch_bounds__(256,2): 256-reg/wave cap. R1 proved this spill-free
// (128 arch + 96 acc = 224). (256,3) and (256,4) both forced acc spill ->
// 1.1-1.3 GB HBM scratch round-trip, 2.5x slower (R2/R3 post-mortems).
__global__ __launch_bounds__(256, 2) void cnf_kernel(
        const float* __restrict__ xin, const float* __restrict__ W1,
        const float* __restrict__ b2, const float* __restrict__ W3,
        const float* __restrict__ b3, const float* __restrict__ osc,
        const float* __restrict__ a1, const float* __restrict__ rsv,
        const ushort* __restrict__ wsw0, const ushort* __restrict__ wswd,
        float* __restrict__ out)
{
    __shared__ __align__(16) ushort V[2][P][PADK];   // V0=h1, V1=g1 (bf16)
    __shared__ float a1s[HH], rsS[HH], wx0s[HH], wx1s[HH], wts[HH];
    __shared__ float X0[P], X1[P], C[P];
    __shared__ float sums[4][P][3];                  // per-wave partial [v0,v1,div]

    const int tid = threadIdx.x;
    const int lane = tid & 63;
    const int w = tid >> 6;
    const int r15 = lane & 15;
    const int q = lane >> 4;
    const int blk = blockIdx.x;
    const int b = blk >> 6;                          // 64 blocks per batch
    const int pbase = blk * P;

    if (tid < HH) {
        a1s[tid] = a1[b * HH + tid];
        rsS[tid] = rsv[tid];
        wx0s[tid] = W1[tid * DIN + 0];
        wx1s[tid] = W1[tid * DIN + 1];
        wts[tid]  = W1[tid * DIN + 2];
    }
    if (tid < P) {
        int gp = pbase + tid;
        X0[tid] = xin[gp * 2 + 0];
        X1[tid] = xin[gp * 2 + 1];
        C[tid] = 0.f;                                // log_det == ctx-accumulator
    }
    const float os = osc[0];
    const float b30 = b3[0], b31 = b3[1];
    float w30r[4], w31r[4], b2r[4];
    #pragma unroll
    for (int n = 0; n < 4; ++n) {
        int j = (w * 4 + n) * 16 + r15;              // this lane's output column
        w30r[n] = W3[j];
        w31r[n] = W3[HH + j];
        b2r[n] = b2[j];
    }
    const ushort* bp0 = wsw0 + (size_t)(w * 4) * 4096 + (size_t)lane * 8;
    const ushort* bpd = wswd + (size_t)(w * 4) * 4096 + (size_t)lane * 8;
    __syncthreads();

    const int hp = tid & 127;
    const int h0 = hp * 2;
    const int pst = tid >> 7;

    for (int s = 0; s < STEPS; ++s) {
        const float tcur = (float)s * DT;

        // ---- phase 1: collapsed layer-1; store h1 and g1 as bf16 A-tiles ----
        {
            float wa = wx0s[h0], wb = wx0s[h0 + 1];
            float wc = wx1s[h0], wd = wx1s[h0 + 1];
            float ra = rsS[h0],  rb = rsS[h0 + 1];
            float ba  = a1s[h0]     + wts[h0]     * tcur;
            float bbv = a1s[h0 + 1] + wts[h0 + 1] * tcur;
            #pragma unroll
            for (int i = 0; i < 16; ++i) {
                int p = pst + 2 * i;
                float x0 = X0[p], x1 = X1[p], cc = C[p];
                float pa = ba  + wa * x0 + wc * x1 + ra * cc;
                float pb = bbv + wb * x0 + wd * x1 + rb * cc;
                float ha = tanh_fast(pa), hb = tanh_fast(pb);
                float ga = 1.f - ha * ha, gb = 1.f - hb * hb;
                *(uint*)&V[0][p][h0] = packbf2(ha, hb);
                *(uint*)&V[1][p][h0] = packbf2(ga, gb);
            }
        }
        __syncthreads();

        // ---- GEMMs: R0 = h1 @ W2^T, Rd = g1 @ W2d^T  (mfma 16x16x32 bf16) ----
        floatx4 acc[2][2][4];                        // [mat][mt][n]
        #pragma unroll
        for (int m = 0; m < 2; ++m)
            #pragma unroll
            for (int mt = 0; mt < 2; ++mt)
                #pragma unroll
                for (int n = 0; n < 4; ++n)
                    acc[m][mt][n] = (floatx4){0.f, 0.f, 0.f, 0.f};

        #pragma unroll
        for (int kt = 0; kt < 8; ++kt) {
            const int koff = kt * 32 + q * 8;
            #pragma unroll
            for (int m = 0; m < 2; ++m) {
                short8 af0 = *(const short8*)&V[m][r15][koff];
                short8 af1 = *(const short8*)&V[m][16 + r15][koff];
                const ushort* bp = (m == 0 ? bp0 : bpd) + (size_t)kt * 512;
                #pragma unroll
                for (int n = 0; n < 4; ++n) {
                    short8 bfr = *(const short8*)(bp + (size_t)n * 4096);
                    acc[m][0][n] = __builtin_amdgcn_mfma_f32_16x16x32_bf16(af0, bfr, acc[m][0][n], 0, 0, 0);
                    acc[m][1][n] = __builtin_amdgcn_mfma_f32_16x16x32_bf16(af1, bfr, acc[m][1][n], 0, 0, 0);
                }
            }
        }

        // ---- epilogue: h2/g2, project with W3 (v) + folded div, reduce j ----
        #pragma unroll
        for (int mt = 0; mt < 2; ++mt) {
            float sv0[4] = {0,0,0,0}, sv1[4] = {0,0,0,0}, sdv[4] = {0,0,0,0};
            #pragma unroll
            for (int n = 0; n < 4; ++n) {
                float w0 = w30r[n], w1 = w31r[n], bbj = b2r[n];
                #pragma unroll
                for (int r = 0; r < 4; ++r) {
                    float h2 = tanh_fast(acc[0][mt][n][r] + bbj);
                    float g2 = 1.f - h2 * h2;
                    sv0[r] += h2 * w0;
                    sv1[r] += h2 * w1;
                    sdv[r] += g2 * acc[1][mt][n][r];
                }
            }
            #pragma unroll
            for (int r = 0; r < 4; ++r) {
                float ta = sv0[r], tb = sv1[r], td = sdv[r];
                #pragma unroll
                for (int off = 1; off < 16; off <<= 1) {
                    ta += __shfl_xor(ta, off);
                    tb += __shfl_xor(tb, off);
                    td += __shfl_xor(td, off);
                }
                if (r15 == 0) {
                    int p = mt * 16 + q * 4 + r;
                    sums[w][p][0] = ta;
                    sums[w][p][1] = tb;
                    sums[w][p][2] = td;
                }
            }
        }
        __syncthreads();

        // ---- state update (Euler) ----
        if (tid < P) {
            float s0 = sums[0][tid][0] + sums[1][tid][0] + sums[2][tid][0] + sums[3][tid][0];
            float s1 = sums[0][tid][1] + sums[1][tid][1] + sums[2][tid][1] + sums[3][tid][1];
            float sd = sums[0][tid][2] + sums[1][tid][2] + sums[2][tid][2] + sums[3][tid][2];
            X0[tid] += (s0 + b30) * os * DT;
            X1[tid] += (s1 + b31) * os * DT;
            C[tid]  += sd * os * DT;
        }
        __syncthreads();
    }

    if (tid < P) {
        int gp = pbase + tid;
        out[gp * 2 + 0] = X0[tid];
        out[gp * 2 + 1] = X1[tid];
        out[NPTS * 2 + gp] = C[tid];      // log_det == C
    }
}

extern "C" void kernel_launch(void* const* d_in, const int* in_sizes, int n_in,
                              void* d_out, int out_size, void* d_ws, size_t ws_size,
                              hipStream_t stream) {
    const float* x   = (const float*)d_in[0];
    const float* z   = (const float*)d_in[1];
    const float* W1  = (const float*)d_in[2];
    const float* b1  = (const float*)d_in[3];
    const float* W2  = (const float*)d_in[4];
    const float* b2  = (const float*)d_in[5];
    const float* W3  = (const float*)d_in[6];
    const float* b3  = (const float*)d_in[7];
    const float* osc = (const float*)d_in[8];

    // ws: a1 [8192 f]@0 | rsv [256 f]@32768B | wsw0 [65536 bf16]@33792B | wswd @164864B
    float* a1   = (float*)d_ws;
    float* rsv  = a1 + 8192;
    ushort* wsw0 = (ushort*)((char*)d_ws + 33792);
    ushort* wswd = (ushort*)((char*)d_ws + 164864);

    hipLaunchKernelGGL(prep_kernel, dim3(64), dim3(256), 0, stream,
                       z, W1, b1, W2, W3, a1, rsv, wsw0, wswd);
    hipLaunchKernelGGL(cnf_kernel, dim3(2048), dim3(256), 0, stream,
                       x, W1, b2, W3, b3, osc, a1, rsv, wsw0, wswd, (float*)d_out);
}

// Round 5
// 385.182 us; speedup vs baseline: 1.6255x; 1.0456x over previous
//
#include <hip/hip_runtime.h>

#define NPTS 65536          // B*N = 32*2048
#define HH 256
#define DIN 131
#define LAT 128
#define STEPS 5
#define DT 0.2f
#define P 32                // points per block
#define PADK 264            // padded row length (bf16 elems)

typedef unsigned int uint;
typedef unsigned short ushort;
typedef __attribute__((ext_vector_type(8))) short short8;
typedef __attribute__((ext_vector_type(4))) float floatx4;

__device__ __forceinline__ float tanh_fast(float x) {
    // tanh(x) = 1 - 2/(exp2(2x*log2e)+1); exact at both saturated ends.
    float e = __builtin_amdgcn_exp2f(x * 2.8853900817779268f);
    return 1.0f - 2.0f * __builtin_amdgcn_rcpf(e + 1.0f);
}

__device__ __forceinline__ ushort f2bf(float f) {
    uint u = __builtin_bit_cast(uint, f);
    u += 0x7fffu + ((u >> 16) & 1u);   // RNE
    return (ushort)(u >> 16);
}

// pack two f32 -> bf16x2 (RNE) with a single v_perm_b32 merge
__device__ __forceinline__ uint packbf2(float a, float b) {
    uint ua = __builtin_bit_cast(uint, a); ua += 0x7fffu + ((ua >> 16) & 1u);
    uint ub = __builtin_bit_cast(uint, b); ub += 0x7fffu + ((ub >> 16) & 1u);
    return __builtin_amdgcn_perm(ub, ua, 0x07060302u);
}

// prep:
//  a1[b][h] = b1[h] + sum_l z[b][l]*W1[h][3+l];  rs[h] = sum_l W1[h][3+l]
//  mw = MERGED bf16 B-frags for W2 and W2d, wave-sliced contiguous:
//    mw[w*32768 + ((ntl*8+kt)*2+mat)*512 + lane*8 + i]
//      = M_mat[(w*4+ntl)*16+(lane&15)][kt*32+(lane>>4)*8+i]
//    mat0 = W2; mat1 = W2d, W2d[j][h] = W2[j][h]*(W1[h][0]*W3[0][j]+W1[h][1]*W3[1][j])
//  R4 post-mortem: separate wsw0/wswd arrays exactly 128 KB apart -> L2 set
//  aliasing -> 24-50% miss -> 0.6-1.3 GB HBM refetch. Merged adjacent layout
//  (mat frags 1 KB apart, one contiguous 64 KB stream per wave) fixes that.
__global__ void prep_kernel(const float* __restrict__ z, const float* __restrict__ W1,
                            const float* __restrict__ b1, const float* __restrict__ W2,
                            const float* __restrict__ W3,
                            float* __restrict__ a1, float* __restrict__ rsv,
                            ushort* __restrict__ mw)
{
    int tid = blockIdx.x * 256 + threadIdx.x;
    if (tid < 8192) {
        int b = tid >> 8, h = tid & 255;
        const float* wrow = W1 + h * DIN + 3;
        const float* zb = z + b * LAT;
        float s = b1[h], r = 0.f;
        for (int l = 0; l < LAT; ++l) { float wv = wrow[l]; s += wv * zb[l]; r += wv; }
        a1[tid] = s;
        if (b == 0) rsv[h] = r;
    } else {
        int t = tid - 8192;                    // 0..8191
        int lane = t & 63, kt = (t >> 6) & 7, nt = t >> 9;   // nt 0..15
        int w = nt >> 2, ntl = nt & 3;
        int j = nt * 16 + (lane & 15);
        int k0 = kt * 32 + (lane >> 4) * 8;
        float w30 = W3[j], w31 = W3[HH + j];
        const float* src = W2 + j * HH + k0;
        ushort* d0 = mw + (size_t)w * 32768 + (size_t)((ntl * 8 + kt) * 2 + 0) * 512 + lane * 8;
        ushort* dd = d0 + 512;                 // mat1 adjacent (1 KB)
        #pragma unroll
        for (int i = 0; i < 8; ++i) {
            int k = k0 + i;
            float wv = src[i];
            d0[i] = f2bf(wv);
            dd[i] = f2bf(wv * (W1[k * DIN] * w30 + W1[k * DIN + 1] * w31));
        }
    }
}

// __launch_bounds__(256,2): 256-reg/wave cap — the only proven non-spilling
// config for this kernel family (R2: (256,4) and R3: (256,3) both spilled
// catastrophically; R4 at (256,2) showed VGPR=128+64acc=192, no spill).
__global__ __launch_bounds__(256, 2) void cnf_kernel(
        const float* __restrict__ xin, const float* __restrict__ W1,
        const float* __restrict__ b2, const float* __restrict__ W3,
        const float* __restrict__ b3, const float* __restrict__ osc,
        const float* __restrict__ a1, const float* __restrict__ rsv,
        const ushort* __restrict__ mw, float* __restrict__ out)
{
    __shared__ __align__(16) ushort V[2][P][PADK];   // V0=h1, V1=g1 (bf16)
    __shared__ float a1s[HH], rsS[HH], wx0s[HH], wx1s[HH], wts[HH];
    __shared__ float X0[P], X1[P], C[P];
    __shared__ float sums[4][P][3];                  // per-wave partial [v0,v1,div]

    const int tid = threadIdx.x;
    const int lane = tid & 63;
    const int w = tid >> 6;
    const int r15 = lane & 15;
    const int q = lane >> 4;
    const int blk = blockIdx.x;
    const int b = blk >> 6;                          // 64 blocks per batch
    const int pbase = blk * P;

    if (tid < HH) {
        a1s[tid] = a1[b * HH + tid];
        rsS[tid] = rsv[tid];
        wx0s[tid] = W1[tid * DIN + 0];
        wx1s[tid] = W1[tid * DIN + 1];
        wts[tid]  = W1[tid * DIN + 2];
    }
    if (tid < P) {
        int gp = pbase + tid;
        X0[tid] = xin[gp * 2 + 0];
        X1[tid] = xin[gp * 2 + 1];
        C[tid] = 0.f;                                // log_det == ctx-accumulator
    }
    const float os = osc[0];
    const float b30 = b3[0], b31 = b3[1];
    float w30r[4], w31r[4], b2r[4];
    #pragma unroll
    for (int n = 0; n < 4; ++n) {
        int j = (w * 4 + n) * 16 + r15;              // this lane's output column
        w30r[n] = W3[j];
        w31r[n] = W3[HH + j];
        b2r[n] = b2[j];
    }
    const ushort* bpw = mw + (size_t)w * 32768 + (size_t)lane * 8;  // wave's 64 KB slice
    __syncthreads();

    const int hp = tid & 127;
    const int h0 = hp * 2;
    const int pst = tid >> 7;

    for (int s = 0; s < STEPS; ++s) {
        const float tcur = (float)s * DT;

        // ---- phase 1: collapsed layer-1; store h1 and g1 as bf16 A-tiles ----
        {
            float wa = wx0s[h0], wb = wx0s[h0 + 1];
            float wc = wx1s[h0], wd = wx1s[h0 + 1];
            float ra = rsS[h0],  rb = rsS[h0 + 1];
            float ba  = a1s[h0]     + wts[h0]     * tcur;
            float bbv = a1s[h0 + 1] + wts[h0 + 1] * tcur;
            #pragma unroll
            for (int i = 0; i < 16; ++i) {
                int p = pst + 2 * i;
                float x0 = X0[p], x1 = X1[p], cc = C[p];
                float pa = ba  + wa * x0 + wc * x1 + ra * cc;
                float pb = bbv + wb * x0 + wd * x1 + rb * cc;
                float ha = tanh_fast(pa), hb = tanh_fast(pb);
                float ga = 1.f - ha * ha, gb = 1.f - hb * hb;
                *(uint*)&V[0][p][h0] = packbf2(ha, hb);
                *(uint*)&V[1][p][h0] = packbf2(ga, gb);
            }
        }
        __syncthreads();

        // ---- GEMMs: R0 = h1 @ W2^T, Rd = g1 @ W2d^T  (mfma 16x16x32 bf16) ----
        floatx4 acc[2][2][4];                        // [mat][mt][n]
        #pragma unroll
        for (int m = 0; m < 2; ++m)
            #pragma unroll
            for (int mt = 0; mt < 2; ++mt)
                #pragma unroll
                for (int n = 0; n < 4; ++n)
                    acc[m][mt][n] = (floatx4){0.f, 0.f, 0.f, 0.f};

        #pragma unroll
        for (int kt = 0; kt < 8; ++kt) {
            const int koff = kt * 32 + q * 8;
            short8 af00 = *(const short8*)&V[0][r15][koff];
            short8 af01 = *(const short8*)&V[0][16 + r15][koff];
            short8 af10 = *(const short8*)&V[1][r15][koff];
            short8 af11 = *(const short8*)&V[1][16 + r15][koff];
            #pragma unroll
            for (int n = 0; n < 4; ++n) {
                const ushort* p = bpw + (size_t)((n * 8 + kt) * 2) * 512;
                short8 bf0 = *(const short8*)p;
                short8 bfd = *(const short8*)(p + 512);
                acc[0][0][n] = __builtin_amdgcn_mfma_f32_16x16x32_bf16(af00, bf0, acc[0][0][n], 0, 0, 0);
                acc[0][1][n] = __builtin_amdgcn_mfma_f32_16x16x32_bf16(af01, bf0, acc[0][1][n], 0, 0, 0);
                acc[1][0][n] = __builtin_amdgcn_mfma_f32_16x16x32_bf16(af10, bfd, acc[1][0][n], 0, 0, 0);
                acc[1][1][n] = __builtin_amdgcn_mfma_f32_16x16x32_bf16(af11, bfd, acc[1][1][n], 0, 0, 0);
            }
        }

        // ---- epilogue: h2/g2, project with W3 (v) + folded div, reduce j ----
        #pragma unroll
        for (int mt = 0; mt < 2; ++mt) {
            float sv0[4] = {0,0,0,0}, sv1[4] = {0,0,0,0}, sdv[4] = {0,0,0,0};
            #pragma unroll
            for (int n = 0; n < 4; ++n) {
                float w0 = w30r[n], w1 = w31r[n], bbj = b2r[n];
                #pragma unroll
                for (int r = 0; r < 4; ++r) {
                    float h2 = tanh_fast(acc[0][mt][n][r] + bbj);
                    float g2 = 1.f - h2 * h2;
                    sv0[r] += h2 * w0;
                    sv1[r] += h2 * w1;
                    sdv[r] += g2 * acc[1][mt][n][r];
                }
            }
            #pragma unroll
            for (int r = 0; r < 4; ++r) {
                float ta = sv0[r], tb = sv1[r], td = sdv[r];
                #pragma unroll
                for (int off = 1; off < 16; off <<= 1) {
                    ta += __shfl_xor(ta, off);
                    tb += __shfl_xor(tb, off);
                    td += __shfl_xor(td, off);
                }
                if (r15 == 0) {
                    int p = mt * 16 + q * 4 + r;
                    sums[w][p][0] = ta;
                    sums[w][p][1] = tb;
                    sums[w][p][2] = td;
                }
            }
        }
        __syncthreads();

        // ---- state update (Euler) ----
        if (tid < P) {
            float s0 = sums[0][tid][0] + sums[1][tid][0] + sums[2][tid][0] + sums[3][tid][0];
            float s1 = sums[0][tid][1] + sums[1][tid][1] + sums[2][tid][1] + sums[3][tid][1];
            float sd = sums[0][tid][2] + sums[1][tid][2] + sums[2][tid][2] + sums[3][tid][2];
            X0[tid] += (s0 + b30) * os * DT;
            X1[tid] += (s1 + b31) * os * DT;
            C[tid]  += sd * os * DT;
        }
        __syncthreads();
    }

    if (tid < P) {
        int gp = pbase + tid;
        out[gp * 2 + 0] = X0[tid];
        out[gp * 2 + 1] = X1[tid];
        out[NPTS * 2 + gp] = C[tid];      // log_det == C
    }
}

extern "C" void kernel_launch(void* const* d_in, const int* in_sizes, int n_in,
                              void* d_out, int out_size, void* d_ws, size_t ws_size,
                              hipStream_t stream) {
    const float* x   = (const float*)d_in[0];
    const float* z   = (const float*)d_in[1];
    const float* W1  = (const float*)d_in[2];
    const float* b1  = (const float*)d_in[3];
    const float* W2  = (const float*)d_in[4];
    const float* b2  = (const float*)d_in[5];
    const float* W3  = (const float*)d_in[6];
    const float* b3  = (const float*)d_in[7];
    const float* osc = (const float*)d_in[8];

    // ws: a1 [8192 f]@0 | rsv [256 f]@32768B | mw [131072 bf16]@33792B (total 295936 B)
    float* a1   = (float*)d_ws;
    float* rsv  = a1 + 8192;
    ushort* mw  = (ushort*)((char*)d_ws + 33792);

    hipLaunchKernelGGL(prep_kernel, dim3(64), dim3(256), 0, stream,
                       z, W1, b1, W2, W3, a1, rsv, mw);
    hipLaunchKernelGGL(cnf_kernel, dim3(2048), dim3(256), 0, stream,
                       x, W1, b2, W3, b3, osc, a1, rsv, mw, (float*)d_out);
}

// Round 6
// 301.077 us; speedup vs baseline: 2.0796x; 1.2793x over previous
//
#include <hip/hip_runtime.h>

#define NPTS 65536          // B*N = 32*2048
#define HH 256
#define DIN 131
#define LAT 128
#define STEPS 5
#define DT 0.2f
#define P 32                // points per block
#define PADK 264            // padded row length (bf16 elems)

typedef unsigned int uint;
typedef unsigned short ushort;
typedef __attribute__((ext_vector_type(8))) short short8;
typedef __attribute__((ext_vector_type(4))) float floatx4;

__device__ __forceinline__ float tanh_fast(float x) {
    // tanh(x) = 1 - 2/(exp2(2x*log2e)+1); exact at both saturated ends.
    float e = __builtin_amdgcn_exp2f(x * 2.8853900817779268f);
    return 1.0f - 2.0f * __builtin_amdgcn_rcpf(e + 1.0f);
}

__device__ __forceinline__ ushort f2bf(float f) {
    uint u = __builtin_bit_cast(uint, f);
    u += 0x7fffu + ((u >> 16) & 1u);   // RNE
    return (ushort)(u >> 16);
}

// pack two f32 -> bf16x2 (RNE) with a single v_perm_b32 merge
__device__ __forceinline__ uint packbf2(float a, float b) {
    uint ua = __builtin_bit_cast(uint, a); ua += 0x7fffu + ((ua >> 16) & 1u);
    uint ub = __builtin_bit_cast(uint, b); ub += 0x7fffu + ((ub >> 16) & 1u);
    return __builtin_amdgcn_perm(ub, ua, 0x07060302u);
}

// prep:
//  a1[b][h] = b1[h] + sum_l z[b][l]*W1[h][3+l];  rs[h] = sum_l W1[h][3+l]
//  mw = MERGED bf16 B-frags for W2 and W2d, wave-sliced contiguous:
//    mw[w*32768 + ((ntl*8+kt)*2+mat)*512 + lane*8 + i]
//      = M_mat[(w*4+ntl)*16+(lane&15)][kt*32+(lane>>4)*8+i]
//    mat0 = W2; mat1 = W2d, W2d[j][h] = W2[j][h]*(W1[h][0]*W3[0][j]+W1[h][1]*W3[1][j])
__global__ void prep_kernel(const float* __restrict__ z, const float* __restrict__ W1,
                            const float* __restrict__ b1, const float* __restrict__ W2,
                            const float* __restrict__ W3,
                            float* __restrict__ a1, float* __restrict__ rsv,
                            ushort* __restrict__ mw)
{
    int tid = blockIdx.x * 256 + threadIdx.x;
    if (tid < 8192) {
        int b = tid >> 8, h = tid & 255;
        const float* wrow = W1 + h * DIN + 3;
        const float* zb = z + b * LAT;
        float s = b1[h], r = 0.f;
        for (int l = 0; l < LAT; ++l) { float wv = wrow[l]; s += wv * zb[l]; r += wv; }
        a1[tid] = s;
        if (b == 0) rsv[h] = r;
    } else {
        int t = tid - 8192;                    // 0..8191
        int lane = t & 63, kt = (t >> 6) & 7, nt = t >> 9;   // nt 0..15
        int w = nt >> 2, ntl = nt & 3;
        int j = nt * 16 + (lane & 15);
        int k0 = kt * 32 + (lane >> 4) * 8;
        float w30 = W3[j], w31 = W3[HH + j];
        const float* src = W2 + j * HH + k0;
        ushort* d0 = mw + (size_t)w * 32768 + (size_t)((ntl * 8 + kt) * 2 + 0) * 512 + lane * 8;
        ushort* dd = d0 + 512;                 // mat1 adjacent (1 KB)
        #pragma unroll
        for (int i = 0; i < 8; ++i) {
            int k = k0 + i;
            float wv = src[i];
            d0[i] = f2bf(wv);
            dd[i] = f2bf(wv * (W1[k * DIN] * w30 + W1[k * DIN + 1] * w31));
        }
    }
}

// __launch_bounds__(256,1): R2-R5 post-mortems — EVERY tighter bound caused
// scratch spill (WRITE_SIZE = threads x 512B at (256,2); threads x ~1KB at
// (256,3)/(256,4)), because true live-range peak is ~190-220 unified regs.
// (256,1) gives the allocator the full 512-reg budget -> no spill; actual
// occupancy still lands at 2 waves/EU (512/~220) = 2 blocks/CU via LDS/VGPR.
__global__ __launch_bounds__(256, 1) void cnf_kernel(
        const float* __restrict__ xin, const float* __restrict__ W1,
        const float* __restrict__ b2, const float* __restrict__ W3,
        const float* __restrict__ b3, const float* __restrict__ osc,
        const float* __restrict__ a1, const float* __restrict__ rsv,
        const ushort* __restrict__ mw, float* __restrict__ out)
{
    __shared__ __align__(16) ushort V[2][P][PADK];   // V0=h1, V1=g1 (bf16)
    __shared__ float a1s[HH], rsS[HH], wx0s[HH], wx1s[HH], wts[HH];
    __shared__ float X0[P], X1[P], C[P];
    __shared__ float sums[4][P][3];                  // per-wave partial [v0,v1,div]

    const int tid = threadIdx.x;
    const int lane = tid & 63;
    const int w = tid >> 6;
    const int r15 = lane & 15;
    const int q = lane >> 4;
    const int blk = blockIdx.x;
    const int b = blk >> 6;                          // 64 blocks per batch
    const int pbase = blk * P;

    if (tid < HH) {
        a1s[tid] = a1[b * HH + tid];
        rsS[tid] = rsv[tid];
        wx0s[tid] = W1[tid * DIN + 0];
        wx1s[tid] = W1[tid * DIN + 1];
        wts[tid]  = W1[tid * DIN + 2];
    }
    if (tid < P) {
        int gp = pbase + tid;
        X0[tid] = xin[gp * 2 + 0];
        X1[tid] = xin[gp * 2 + 1];
        C[tid] = 0.f;                                // log_det == ctx-accumulator
    }
    const float os = osc[0];
    const float b30 = b3[0], b31 = b3[1];
    float w30r[4], w31r[4], b2r[4];
    #pragma unroll
    for (int n = 0; n < 4; ++n) {
        int j = (w * 4 + n) * 16 + r15;              // this lane's output column
        w30r[n] = W3[j];
        w31r[n] = W3[HH + j];
        b2r[n] = b2[j];
    }
    const ushort* bpw = mw + (size_t)w * 32768 + (size_t)lane * 8;  // wave's 64 KB slice
    __syncthreads();

    const int hp = tid & 127;
    const int h0 = hp * 2;
    const int pst = tid >> 7;

    for (int s = 0; s < STEPS; ++s) {
        const float tcur = (float)s * DT;

        // ---- phase 1: collapsed layer-1; store h1 and g1 as bf16 A-tiles ----
        {
            float wa = wx0s[h0], wb = wx0s[h0 + 1];
            float wc = wx1s[h0], wd = wx1s[h0 + 1];
            float ra = rsS[h0],  rb = rsS[h0 + 1];
            float ba  = a1s[h0]     + wts[h0]     * tcur;
            float bbv = a1s[h0 + 1] + wts[h0 + 1] * tcur;
            #pragma unroll
            for (int i = 0; i < 16; ++i) {
                int p = pst + 2 * i;
                float x0 = X0[p], x1 = X1[p], cc = C[p];
                float pa = ba  + wa * x0 + wc * x1 + ra * cc;
                float pb = bbv + wb * x0 + wd * x1 + rb * cc;
                float ha = tanh_fast(pa), hb = tanh_fast(pb);
                float ga = 1.f - ha * ha, gb = 1.f - hb * hb;
                *(uint*)&V[0][p][h0] = packbf2(ha, hb);
                *(uint*)&V[1][p][h0] = packbf2(ga, gb);
            }
        }
        __syncthreads();

        // ---- GEMMs: R0 = h1 @ W2^T, Rd = g1 @ W2d^T  (mfma 16x16x32 bf16) ----
        floatx4 acc[2][2][4];                        // [mat][mt][n]
        #pragma unroll
        for (int m = 0; m < 2; ++m)
            #pragma unroll
            for (int mt = 0; mt < 2; ++mt)
                #pragma unroll
                for (int n = 0; n < 4; ++n)
                    acc[m][mt][n] = (floatx4){0.f, 0.f, 0.f, 0.f};

        #pragma unroll
        for (int kt = 0; kt < 8; ++kt) {
            const int koff = kt * 32 + q * 8;
            short8 af00 = *(const short8*)&V[0][r15][koff];
            short8 af01 = *(const short8*)&V[0][16 + r15][koff];
            short8 af10 = *(const short8*)&V[1][r15][koff];
            short8 af11 = *(const short8*)&V[1][16 + r15][koff];
            #pragma unroll
            for (int n = 0; n < 4; ++n) {
                const ushort* p = bpw + (size_t)((n * 8 + kt) * 2) * 512;
                short8 bf0 = *(const short8*)p;
                short8 bfd = *(const short8*)(p + 512);
                acc[0][0][n] = __builtin_amdgcn_mfma_f32_16x16x32_bf16(af00, bf0, acc[0][0][n], 0, 0, 0);
                acc[0][1][n] = __builtin_amdgcn_mfma_f32_16x16x32_bf16(af01, bf0, acc[0][1][n], 0, 0, 0);
                acc[1][0][n] = __builtin_amdgcn_mfma_f32_16x16x32_bf16(af10, bfd, acc[1][0][n], 0, 0, 0);
                acc[1][1][n] = __builtin_amdgcn_mfma_f32_16x16x32_bf16(af11, bfd, acc[1][1][n], 0, 0, 0);
            }
        }

        // ---- epilogue: h2/g2, project with W3 (v) + folded div, reduce j ----
        #pragma unroll
        for (int mt = 0; mt < 2; ++mt) {
            float sv0[4] = {0,0,0,0}, sv1[4] = {0,0,0,0}, sdv[4] = {0,0,0,0};
            #pragma unroll
            for (int n = 0; n < 4; ++n) {
                float w0 = w30r[n], w1 = w31r[n], bbj = b2r[n];
                #pragma unroll
                for (int r = 0; r < 4; ++r) {
                    float h2 = tanh_fast(acc[0][mt][n][r] + bbj);
                    float g2 = 1.f - h2 * h2;
                    sv0[r] += h2 * w0;
                    sv1[r] += h2 * w1;
                    sdv[r] += g2 * acc[1][mt][n][r];
                }
            }
            #pragma unroll
            for (int r = 0; r < 4; ++r) {
                float ta = sv0[r], tb = sv1[r], td = sdv[r];
                #pragma unroll
                for (int off = 1; off < 16; off <<= 1) {
                    ta += __shfl_xor(ta, off);
                    tb += __shfl_xor(tb, off);
                    td += __shfl_xor(td, off);
                }
                if (r15 == 0) {
                    int p = mt * 16 + q * 4 + r;
                    sums[w][p][0] = ta;
                    sums[w][p][1] = tb;
                    sums[w][p][2] = td;
                }
            }
        }
        __syncthreads();

        // ---- state update (Euler) ----
        if (tid < P) {
            float s0 = sums[0][tid][0] + sums[1][tid][0] + sums[2][tid][0] + sums[3][tid][0];
            float s1 = sums[0][tid][1] + sums[1][tid][1] + sums[2][tid][1] + sums[3][tid][1];
            float sd = sums[0][tid][2] + sums[1][tid][2] + sums[2][tid][2] + sums[3][tid][2];
            X0[tid] += (s0 + b30) * os * DT;
            X1[tid] += (s1 + b31) * os * DT;
            C[tid]  += sd * os * DT;
        }
        __syncthreads();
    }

    if (tid < P) {
        int gp = pbase + tid;
        out[gp * 2 + 0] = X0[tid];
        out[gp * 2 + 1] = X1[tid];
        out[NPTS * 2 + gp] = C[tid];      // log_det == C
    }
}

extern "C" void kernel_launch(void* const* d_in, const int* in_sizes, int n_in,
                              void* d_out, int out_size, void* d_ws, size_t ws_size,
                              hipStream_t stream) {
    const float* x   = (const float*)d_in[0];
    const float* z   = (const float*)d_in[1];
    const float* W1  = (const float*)d_in[2];
    const float* b1  = (const float*)d_in[3];
    const float* W2  = (const float*)d_in[4];
    const float* b2  = (const float*)d_in[5];
    const float* W3  = (const float*)d_in[6];
    const float* b3  = (const float*)d_in[7];
    const float* osc = (const float*)d_in[8];

    // ws: a1 [8192 f]@0 | rsv [256 f]@32768B | mw [131072 bf16]@33792B (total 295936 B)
    float* a1   = (float*)d_ws;
    float* rsv  = a1 + 8192;
    ushort* mw  = (ushort*)((char*)d_ws + 33792);

    hipLaunchKernelGGL(prep_kernel, dim3(64), dim3(256), 0, stream,
                       z, W1, b1, W2, W3, a1, rsv, mw);
    hipLaunchKernelGGL(cnf_kernel, dim3(2048), dim3(256), 0, stream,
                       x, W1, b2, W3, b3, osc, a1, rsv, mw, (float*)d_out);
}